// Round 1
// baseline (211.007 us; speedup 1.0000x reference)
//
#include <hip/hip_runtime.h>

// ExLlama q4: T=32, K=8192, N=28672, group=128.
// Harness promotes fp16 reference arrays to float32; output is float32.
//
// FULL-K RESTRUCTURE (vs previous split-K=16 + ws + reduce kernel):
// the rocprof top-5 was dominated by 448-MiB workspace poison fills (~68 us
// each) and the reduce kernel added a 62-MB round trip. This version uses
// NO workspace, NO atomics, NO second dispatch:
//   grid = N/64 = 448 blocks x 256 threads; each wave owns 16 columns x all
//   32 tokens; K is streamed through LDS in 32 double-buffered phases of
//   256 k. Every block is co-resident (448 < 256 CUs * 4 blocks by LDS), so
//   per-phase prefetch (~2600 cyc/phase >> 900 cyc HBM latency) hides loads.
// Carried over verified pieces: 0x6400 nibble dequant (bit-exact vs fp16
// reference), pkrtz pair-permuted x staging, MFMA 16x16x32 f16 fragment
// mapping (A: m=lane&15, k=quad*8+perm; D: col=lane&15, row=quad*4+reg).
#define T_TOK   32
#define KDIM    8192
#define NDIM    28672
#define NZW     3584             // N / 8
#define PHK     256              // k per phase
#define NPH     (KDIM / PHK)     // 32 phases
#define GPP     (PHK / 128)      // 2 quant-groups per phase
#define XROW    (PHK + 8)        // padded LDS row stride (halves): 264
#define XIT     ((T_TOK * PHK) / (256 * 8))   // 4 staging iters/thread

typedef _Float16 half8  __attribute__((ext_vector_type(8)));
typedef _Float16 half2v __attribute__((ext_vector_type(2)));
typedef float    f32x4  __attribute__((ext_vector_type(4)));
typedef unsigned uint4v __attribute__((ext_vector_type(4)));

__global__ __launch_bounds__(256)
void exllama_gemm_fullk(const int*   __restrict__ qweight,
                        const int*   __restrict__ qzeros,
                        const float* __restrict__ scales,
                        const float* __restrict__ x,
                        const float* __restrict__ bias,
                        float*       __restrict__ out)
{
    __shared__ alignas(16) _Float16 xs[2][T_TOK * XROW];   // 2 x 16.5 KB

    const int tid  = threadIdx.x;
    const int lane = tid & 63;
    const int wav  = tid >> 6;
    const int quad = lane >> 4;
    const int l16  = lane & 15;
    const int n    = blockIdx.x * 64 + wav * 16 + l16;   // this lane's column

    // ---- phase-invariant addresses ----
    const float* xbase[XIT];
    int          lofs[XIT];
    #pragma unroll
    for (int it = 0; it < XIT; ++it) {
        const int e  = it * 2048 + tid * 8;      // half-index within 32x256 tile
        const int t  = e >> 8;                   // token row
        const int kl = e & (PHK - 1);
        xbase[it] = x + (size_t)t * KDIM + kl;
        lofs[it]  = t * XROW + kl;
    }

    f32x4 xlo[XIT], xhi[XIT];
    auto LOADX = [&](int p) {
        #pragma unroll
        for (int it = 0; it < XIT; ++it) {
            const float* xp = xbase[it] + p * PHK;
            xlo[it] = *(const f32x4*)xp;
            xhi[it] = *(const f32x4*)(xp + 4);
        }
    };
    auto CVTW = [&](_Float16* buf) {
        #pragma unroll
        for (int it = 0; it < XIT; ++it) {
            uint4v u;
            #pragma unroll
            for (int j = 0; j < 4; ++j)
                u[j] = __builtin_bit_cast(unsigned,
                          __builtin_amdgcn_cvt_pkrtz(xlo[it][j], xhi[it][j]));
            *(uint4v*)(buf + lofs[it]) = u;
        }
    };
    auto LOADQ = [&](unsigned* qw, half2v* sp, half2v* cp, int p) {
        #pragma unroll
        for (int g = 0; g < GPP; ++g) {
            const size_t rb = (size_t)(p * (PHK / 8) + g * 16 + quad) * NDIM + n;
            #pragma unroll
            for (int c = 0; c < 4; ++c)
                qw[g * 4 + c] = (unsigned)qweight[rb + (size_t)(c * 4) * NDIM];
            const float s  = scales[(size_t)(p * GPP + g) * NDIM + n];
            const int   zw = qzeros[(size_t)(p * GPP + g) * NZW + (n >> 3)];
            const int   z  = (zw >> ((n & 7) * 4)) & 15;
            const _Float16 sh = (_Float16)s;
            const _Float16 ch = (_Float16)(float)(-(1025 + z));
            sp[g] = (half2v){sh, sh};
            cp[g] = (half2v){ch, ch};
        }
    };

    f32x4 acc0 = (f32x4){0.f, 0.f, 0.f, 0.f};
    f32x4 acc1 = (f32x4){0.f, 0.f, 0.f, 0.f};
    auto COMPUTE = [&](const unsigned* qw, const half2v* sp, const half2v* cp,
                       const _Float16* buf) {
        #pragma unroll
        for (int g = 0; g < GPP; ++g) {
            #pragma unroll
            for (int c = 0; c < 4; ++c) {
                const int kloc = g * 128 + c * 32 + quad * 8;
                half8 a0 = *(const half8*)(buf + l16 * XROW + kloc);
                half8 a1 = *(const half8*)(buf + (l16 + 16) * XROW + kloc);
                const unsigned w = qw[g * 4 + c];
                uint4v bu;
                #pragma unroll
                for (int i = 0; i < 4; ++i) {
                    unsigned t = ((w >> (4 * i)) & 0x000F000Fu) | 0x64006400u;
                    half2v th = __builtin_bit_cast(half2v, t);
                    half2v r  = (th + cp[g]) * sp[g];
                    bu[i] = __builtin_bit_cast(unsigned, r);
                }
                half8 bf = __builtin_bit_cast(half8, bu);
                acc0 = __builtin_amdgcn_mfma_f32_16x16x32_f16(a0, bf, acc0, 0, 0, 0);
                acc1 = __builtin_amdgcn_mfma_f32_16x16x32_f16(a1, bf, acc1, 0, 0, 0);
            }
        }
    };

    unsigned qwA[4 * GPP], qwB[4 * GPP];
    half2v   spA[GPP], cpA[GPP], spB[GPP], cpB[GPP];

    // ---- prologue: stage phase 0, prefetch its weights ----
    LOADX(0);
    LOADQ(qwA, spA, cpA, 0);
    CVTW(xs[0]);
    __syncthreads();

    for (int pp = 0; pp < NPH; pp += 2) {
        // even phase: compute from A/xs[0]; prefetch pp+1 into B/xs[1]
        LOADX(pp + 1);
        LOADQ(qwB, spB, cpB, pp + 1);
        COMPUTE(qwA, spA, cpA, xs[0]);
        CVTW(xs[1]);
        __syncthreads();
        // odd phase: compute from B/xs[1]; prefetch pp+2 into A/xs[0]
        if (pp + 2 < NPH) {
            LOADX(pp + 2);
            LOADQ(qwA, spA, cpA, pp + 2);
        }
        COMPUTE(qwB, spB, cpB, xs[1]);
        if (pp + 2 < NPH) CVTW(xs[0]);
        __syncthreads();
    }

    // ---- epilogue: each wave owns its 16 columns fully; fuse bias ----
    const float bb = bias[n];
    #pragma unroll
    for (int r = 0; r < 4; ++r) {
        out[(size_t)(quad * 4 + r) * NDIM + n]        = acc0[r] + bb;
        out[(size_t)(16 + quad * 4 + r) * NDIM + n]   = acc1[r] + bb;
    }
}

extern "C" void kernel_launch(void* const* d_in, const int* in_sizes, int n_in,
                              void* d_out, int out_size, void* d_ws, size_t ws_size,
                              hipStream_t stream)
{
    const float* x  = (const float*)d_in[0];   // (32, 8192) f32 (fp16 promoted)
    const int* qweight = (const int*)d_in[1];  // (1024, 28672) i32
    const int* qzeros  = (const int*)d_in[2];  // (64, 3584) i32
    const float* sc = (const float*)d_in[3];   // (64, 28672) f32
    const float* bs = (const float*)d_in[4];   // (28672,) f32
    float* out      = (float*)d_out;           // (32, 28672) f32

    (void)d_ws; (void)ws_size;                 // workspace deliberately unused
    exllama_gemm_fullk<<<dim3(NDIM / 64), 256, 0, stream>>>(
        qweight, qzeros, sc, x, bs, out);
}

// Round 2
// 206.516 us; speedup vs baseline: 1.0217x; 1.0217x over previous
//
#include <hip/hip_runtime.h>

// ExLlama q4: T=32, K=8192, N=28672, group=128.
// Harness promotes fp16 reference arrays to float32; output is float32.
//
// ROUND-2 THEORY: the two 448-MiB ws poison fills (~68 us each) run every
// iteration REGARDLESS of ws use (round-1 dur 211 = 2x68 + 77.7 kernel), so
// ws is free. Round-1's full-K kernel was latency-bound at 1.75 waves/SIMD
// (Occupancy 16%, MfmaUtil 7%, HBM 12% -- nothing busy). This version:
// KSPLIT=4 quadruples wave count to 28/CU (4 blocks/CU by LDS -> 4
// waves/SIMD resident) while keeping ws down to 14.7 MB (L3-resident for
// the reduce), vs round-0's split-16 with 58.7 MB ws round trip.
// Carried over verified pieces: 0x6400 nibble dequant (bit-exact vs fp16
// reference), pkrtz pair-permuted x staging, MFMA 16x16x32 f16 fragment
// mapping, double-buffered 256-k phases with per-phase register prefetch.
#define T_TOK   32
#define KDIM    8192
#define NDIM    28672
#define NZW     3584             // N / 8
#define PHK     256              // k per phase
#define GPP     (PHK / 128)      // 2 quant-groups per phase
#define XROW    (PHK + 8)        // padded LDS row stride (halves): 264
#define XIT     ((T_TOK * PHK) / (256 * 8))   // 4 staging iters/thread
#define KSPLIT  4

typedef _Float16 half8  __attribute__((ext_vector_type(8)));
typedef _Float16 half2v __attribute__((ext_vector_type(2)));
typedef float    f32x4  __attribute__((ext_vector_type(4)));
typedef unsigned uint4v __attribute__((ext_vector_type(4)));

template<int SPLIT>
__global__ __launch_bounds__(256)
void exllama_gemm(const int*   __restrict__ qweight,
                  const int*   __restrict__ qzeros,
                  const float* __restrict__ scales,
                  const float* __restrict__ x,
                  const float* __restrict__ bias,
                  float*       __restrict__ ws,
                  float*       __restrict__ out)
{
    constexpr int KSEG = KDIM / SPLIT;    // k per block
    constexpr int NPH  = KSEG / PHK;      // phases per block (even)

    __shared__ alignas(16) _Float16 xs[2][T_TOK * XROW];   // 2 x 16.5 KB

    const int tid  = threadIdx.x;
    const int lane = tid & 63;
    const int wav  = tid >> 6;
    const int quad = lane >> 4;
    const int l16  = lane & 15;
    const int n    = blockIdx.x * 64 + wav * 16 + l16;   // this lane's column
    const int seg  = (SPLIT > 1) ? blockIdx.y : 0;
    const int k0   = seg * KSEG;

    // ---- phase-invariant addresses ----
    const float* xbase[XIT];
    int          lofs[XIT];
    #pragma unroll
    for (int it = 0; it < XIT; ++it) {
        const int e  = it * 2048 + tid * 8;      // half-index within 32x256 tile
        const int t  = e >> 8;                   // token row
        const int kl = e & (PHK - 1);
        xbase[it] = x + (size_t)t * KDIM + k0 + kl;
        lofs[it]  = t * XROW + kl;
    }

    f32x4 xlo[XIT], xhi[XIT];
    auto LOADX = [&](int p) {
        #pragma unroll
        for (int it = 0; it < XIT; ++it) {
            const float* xp = xbase[it] + p * PHK;
            xlo[it] = *(const f32x4*)xp;
            xhi[it] = *(const f32x4*)(xp + 4);
        }
    };
    auto CVTW = [&](_Float16* buf) {
        #pragma unroll
        for (int it = 0; it < XIT; ++it) {
            uint4v u;
            #pragma unroll
            for (int j = 0; j < 4; ++j)
                u[j] = __builtin_bit_cast(unsigned,
                          __builtin_amdgcn_cvt_pkrtz(xlo[it][j], xhi[it][j]));
            *(uint4v*)(buf + lofs[it]) = u;
        }
    };
    auto LOADQ = [&](unsigned* qw, half2v* sp, half2v* cp, int p) {
        #pragma unroll
        for (int g = 0; g < GPP; ++g) {
            const int prow = (k0 >> 3) + p * (PHK / 8);        // qweight row base
            const size_t rb = (size_t)(prow + g * 16 + quad) * NDIM + n;
            #pragma unroll
            for (int c = 0; c < 4; ++c)
                qw[g * 4 + c] = (unsigned)qweight[rb + (size_t)(c * 4) * NDIM];
            const int gi = (k0 >> 7) + p * GPP + g;            // quant group
            const float s  = scales[(size_t)gi * NDIM + n];
            const int   zw = qzeros[(size_t)gi * NZW + (n >> 3)];
            const int   z  = (zw >> ((n & 7) * 4)) & 15;
            const _Float16 sh = (_Float16)s;
            const _Float16 ch = (_Float16)(float)(-(1025 + z));
            sp[g] = (half2v){sh, sh};
            cp[g] = (half2v){ch, ch};
        }
    };

    f32x4 acc0 = (f32x4){0.f, 0.f, 0.f, 0.f};
    f32x4 acc1 = (f32x4){0.f, 0.f, 0.f, 0.f};
    auto COMPUTE = [&](const unsigned* qw, const half2v* sp, const half2v* cp,
                       const _Float16* buf) {
        #pragma unroll
        for (int g = 0; g < GPP; ++g) {
            #pragma unroll
            for (int c = 0; c < 4; ++c) {
                const int kloc = g * 128 + c * 32 + quad * 8;
                half8 a0 = *(const half8*)(buf + l16 * XROW + kloc);
                half8 a1 = *(const half8*)(buf + (l16 + 16) * XROW + kloc);
                const unsigned w = qw[g * 4 + c];
                uint4v bu;
                #pragma unroll
                for (int i = 0; i < 4; ++i) {
                    unsigned t = ((w >> (4 * i)) & 0x000F000Fu) | 0x64006400u;
                    half2v th = __builtin_bit_cast(half2v, t);
                    half2v r  = (th + cp[g]) * sp[g];
                    bu[i] = __builtin_bit_cast(unsigned, r);
                }
                half8 bf = __builtin_bit_cast(half8, bu);
                acc0 = __builtin_amdgcn_mfma_f32_16x16x32_f16(a0, bf, acc0, 0, 0, 0);
                acc1 = __builtin_amdgcn_mfma_f32_16x16x32_f16(a1, bf, acc1, 0, 0, 0);
            }
        }
    };

    unsigned qwA[4 * GPP], qwB[4 * GPP];
    half2v   spA[GPP], cpA[GPP], spB[GPP], cpB[GPP];

    // ---- prologue: stage phase 0, prefetch its weights ----
    LOADX(0);
    LOADQ(qwA, spA, cpA, 0);
    CVTW(xs[0]);
    __syncthreads();

    for (int pp = 0; pp < NPH; pp += 2) {
        // even phase: compute from A/xs[0]; prefetch pp+1 into B/xs[1]
        LOADX(pp + 1);
        LOADQ(qwB, spB, cpB, pp + 1);
        COMPUTE(qwA, spA, cpA, xs[0]);
        CVTW(xs[1]);
        __syncthreads();
        // odd phase: compute from B/xs[1]; prefetch pp+2 into A/xs[0]
        if (pp + 2 < NPH) {
            LOADX(pp + 2);
            LOADQ(qwA, spA, cpA, pp + 2);
        }
        COMPUTE(qwB, spB, cpB, xs[1]);
        if (pp + 2 < NPH) CVTW(xs[0]);
        __syncthreads();
    }

    // ---- epilogue ----
    if (SPLIT == 1) {
        const float bb = bias[n];
        #pragma unroll
        for (int r = 0; r < 4; ++r) {
            out[(size_t)(quad * 4 + r) * NDIM + n]      = acc0[r] + bb;
            out[(size_t)(16 + quad * 4 + r) * NDIM + n] = acc1[r] + bb;
        }
    } else {
        float* wsp = ws + (size_t)seg * (T_TOK * NDIM);
        #pragma unroll
        for (int r = 0; r < 4; ++r) {
            wsp[(size_t)(quad * 4 + r) * NDIM + n]      = acc0[r];
            wsp[(size_t)(16 + quad * 4 + r) * NDIM + n] = acc1[r];
        }
    }
}

__global__ __launch_bounds__(256)
void reduce_bias(const float* __restrict__ ws,
                 const float* __restrict__ bias,
                 float*       __restrict__ out)
{
    const int e = (blockIdx.x * 256 + threadIdx.x) * 4;  // 4 consecutive, one row
    const int n = e % NDIM;
    f32x4 sum = (f32x4){0.f, 0.f, 0.f, 0.f};
    #pragma unroll
    for (int s = 0; s < KSPLIT; ++s)
        sum += *(const f32x4*)(ws + (size_t)s * (T_TOK * NDIM) + e);
    f32x4 bb = *(const f32x4*)(bias + n);
    *(f32x4*)(out + e) = sum + bb;
}

extern "C" void kernel_launch(void* const* d_in, const int* in_sizes, int n_in,
                              void* d_out, int out_size, void* d_ws, size_t ws_size,
                              hipStream_t stream)
{
    const float* x  = (const float*)d_in[0];   // (32, 8192) f32 (fp16 promoted)
    const int* qweight = (const int*)d_in[1];  // (1024, 28672) i32
    const int* qzeros  = (const int*)d_in[2];  // (64, 3584) i32
    const float* sc = (const float*)d_in[3];   // (64, 28672) f32
    const float* bs = (const float*)d_in[4];   // (28672,) f32
    float* out      = (float*)d_out;           // (32, 28672) f32

    const size_t need = (size_t)KSPLIT * T_TOK * NDIM * sizeof(float);  // 14.7 MB
    if (ws_size >= need) {
        exllama_gemm<KSPLIT><<<dim3(NDIM / 64, KSPLIT), 256, 0, stream>>>(
            qweight, qzeros, sc, x, bs, (float*)d_ws, out);
        reduce_bias<<<(T_TOK * NDIM) / (256 * 4), 256, 0, stream>>>(
            (const float*)d_ws, bs, out);
    } else {
        // correct fallback: full-K, no ws (round-1 kernel, ~78 us)
        exllama_gemm<1><<<dim3(NDIM / 64), 256, 0, stream>>>(
            qweight, qzeros, sc, x, bs, nullptr, out);
    }
}